// Round 1
// 255.642 us; speedup vs baseline: 1.0705x; 1.0705x over previous
//
#include <hip/hip_runtime.h>
#include <stdint.h>

// ---------------------------------------------------------------------------
// SelfAttention: out = softmax((x Wq^T)(x Wk^T)^T / sqrt(E)) (x Wv^T)
// B=4, S=2048, E=1024. bf16 MFMA, fp32 accumulate.
// R8: replace the 128x128 / 2-barrier ring GEMM (~700 TF, MfmaUtil 28%) with
// the 256-wide 8-wave phase-split schedule (learn_hip m201 lineage):
//  - BK=64, double-buffered LDS (128/96 KB), global_load_lds w16
//  - T2: XOR swizzle (chunk ^= row&7) via pre-swizzled GLOBAL source +
//    swizzled ds_read (LDS itself stays linear -> gll-compatible)
//  - 4 phases per K-tile: {ds_read subtile | stage-issue | barrier |
//    lgkmcnt(0) | setprio(1) | MFMA | setprio(0) | barrier}
//  - staging for tile k+1 front-loaded in phases 0-1; single vmcnt(0) at
//    phase 3 (loads have had 2-3 MFMA phases to land -> near-free drain)
//  - B-fragments held in registers across all 4 phases (24 ds_reads/K-tile)
// Tiles: QKV 256x256 (384 blk), scores 256x256 (256 blk), PV 128x256 (256
// blk -- 256x256 would only fill half the GPU). Numerics identical to R7.
// Dispatches: cast, QKV, scores, softmax, PV.
// ---------------------------------------------------------------------------

typedef __attribute__((ext_vector_type(8))) short bf16x8;   // 8 bf16 = 4 VGPRs
typedef __attribute__((ext_vector_type(4))) float f32x4;

__device__ __forceinline__ float bf2f(uint16_t u) {
    return __uint_as_float(((uint32_t)u) << 16);
}
__device__ __forceinline__ uint16_t f2bf(float f) {
    uint32_t u = __float_as_uint(f);
    uint32_t r = u + 0x7FFFu + ((u >> 16) & 1u);   // RNE
    return (uint16_t)(r >> 16);
}

// async global -> LDS, 16 bytes per lane (wave-uniform base + lane*16)
__device__ __forceinline__ void gll16(const void* g, void* l) {
    __builtin_amdgcn_global_load_lds(
        (const __attribute__((address_space(1))) uint32_t*)g,
        (__attribute__((address_space(3))) uint32_t*)l,
        16, 0, 0);
}

// stage NC 64-row regions (8 KB each, 512 threads x 16 B) into linear LDS.
// Global source is pre-swizzled by the caller (sx column), so reading LDS
// with the same XOR recovers the logical layout (rule 21: both sides).
template <int NC>
__device__ __forceinline__ void stageT(const uint16_t* g, long stride,
                                       uint16_t* l, int tid) {
    #pragma unroll
    for (int c = 0; c < NC; ++c)
        gll16(g + (long)c * 64 * stride, l + c * 4096 + tid * 8);
}

// ---- fused cast: x (NX4 float4s) then stacked Wq|Wk|Wv (NW4 each) ---------
__global__ __launch_bounds__(256) void cast_all(const float* __restrict__ x,
                                                const float* __restrict__ Wq,
                                                const float* __restrict__ Wk,
                                                const float* __restrict__ Wv,
                                                uint16_t* __restrict__ xb,
                                                uint16_t* __restrict__ wqkvb,
                                                int NX4, int NW4) {
    int i = blockIdx.x * 256 + threadIdx.x;
    const float* src;
    uint16_t* dst;
    int off;
    if (i < NX4) {
        src = x; dst = xb; off = i;
    } else {
        int j = i - NX4;
        if (j >= 3 * NW4) return;
        int which = j / NW4;              // 0,1,2
        off = j - which * NW4;
        src = (which == 0) ? Wq : (which == 1) ? Wk : Wv;
        dst = wqkvb + (size_t)which * NW4 * 4;
    }
    float4 v = ((const float4*)src)[off];
    ushort4 o;
    o.x = f2bf(v.x); o.y = f2bf(v.y); o.z = f2bf(v.z); o.w = f2bf(v.w);
    ((ushort4*)dst)[off] = o;
}

// ---- row softmax over 2048 bf16 elements, in place, one block per row -----
__global__ __launch_bounds__(256) void softmax_rows(uint16_t* __restrict__ P) {
    const int n = 2048;
    uint16_t* row = P + (size_t)blockIdx.x * n;
    int tid = threadIdx.x;
    int w = tid >> 6, ln = tid & 63;
    float v[8];
    float m = -3.4e38f;
    #pragma unroll
    for (int i = 0; i < 8; i++) { v[i] = bf2f(row[tid + 256 * i]); m = fmaxf(m, v[i]); }
    #pragma unroll
    for (int o = 32; o >= 1; o >>= 1) m = fmaxf(m, __shfl_down(m, o, 64));
    __shared__ float smax[4], ssum[4];
    if (ln == 0) smax[w] = m;
    __syncthreads();
    m = fmaxf(fmaxf(smax[0], smax[1]), fmaxf(smax[2], smax[3]));
    float s = 0.f;
    #pragma unroll
    for (int i = 0; i < 8; i++) { v[i] = __expf(v[i] - m); s += v[i]; }
    #pragma unroll
    for (int o = 32; o >= 1; o >>= 1) s += __shfl_down(s, o, 64);
    if (ln == 0) ssum[w] = s;
    __syncthreads();
    s = ssum[0] + ssum[1] + ssum[2] + ssum[3];
    float inv = 1.f / s;
    #pragma unroll
    for (int i = 0; i < 8; i++) row[tid + 256 * i] = f2bf(v[i] * inv);
}

// ---- NT GEMM: C[M][N] = alpha * A[M][K] * B[N][K]^T  (bf16 in, OutT out) --
// BM x 256 tile, BK=64, 8 waves (2M x 4N), per-wave (BM/2) x 64 output.
// Phase-split schedule, double-buffered LDS, XOR-swizzled reads.
// Optional: columns >= vcol0 written TRANSPOSED into Vt[b][col-vcol0][row%2048].

#define DS_A(mh_) do { \
    _Pragma("unroll") for (int f_ = 0; f_ < MH; ++f_) { \
        const uint16_t* p_ = Asb + axbase + ((mh_)*MH + f_) * 1024; \
        af[f_][0] = *(const bf16x8*)(p_ + cs0); \
        af[f_][1] = *(const bf16x8*)(p_ + cs1); \
    } } while (0)

#define DS_B(nh_) do { \
    _Pragma("unroll") for (int n_ = 0; n_ < 2; ++n_) { \
        const uint16_t* p_ = Bsb + bxbase + ((nh_)*2 + n_) * 1024; \
        bf[nh_][n_][0] = *(const bf16x8*)(p_ + cs0); \
        bf[nh_][n_][1] = *(const bf16x8*)(p_ + cs1); \
    } } while (0)

#define MMA(mh_, nh_) do { \
    _Pragma("unroll") for (int f_ = 0; f_ < MH; ++f_) { \
        _Pragma("unroll") for (int n_ = 0; n_ < 2; ++n_) { \
            acc[(mh_)*MH + f_][(nh_)*2 + n_] = __builtin_amdgcn_mfma_f32_16x16x32_bf16( \
                af[f_][0], bf[nh_][n_][0], acc[(mh_)*MH + f_][(nh_)*2 + n_], 0, 0, 0); \
            acc[(mh_)*MH + f_][(nh_)*2 + n_] = __builtin_amdgcn_mfma_f32_16x16x32_bf16( \
                af[f_][1], bf[nh_][n_][1], acc[(mh_)*MH + f_][(nh_)*2 + n_], 0, 0, 0); \
        } } } while (0)

#define PH_ENTER do { \
    asm volatile("s_barrier\n\ts_waitcnt lgkmcnt(0)" ::: "memory"); \
    __builtin_amdgcn_s_setprio(1); } while (0)

#define PH_EXIT do { \
    __builtin_amdgcn_s_setprio(0); \
    asm volatile("s_barrier" ::: "memory"); } while (0)

template <int BM, typename OutT>
__global__ __launch_bounds__(512, 2) void gemm_nt(const uint16_t* __restrict__ A,
                                                  const uint16_t* __restrict__ B,
                                                  OutT* __restrict__ C,
                                                  int gx, int gy,
                                                  long lda, long ldb, long ldc,
                                                  int K, float alpha,
                                                  long sA, long sB, long sC,
                                                  uint16_t* __restrict__ VtP,
                                                  int vcol0) {
    constexpr int MF  = BM / 32;   // M fragments per wave
    constexpr int MH  = MF / 2;    // per M-half
    constexpr int NAC = BM / 64;   // A staging calls per K-tile

    // ---- XCD-contiguous swizzle + 4x4 supertile decode (all grids %8==0,
    //      gx%4==0, gy%4==0) ----
    const int total = gridDim.x;
    const int nb  = blockIdx.x;
    const int per = total >> 3;
    const int g   = (nb & 7) * per + (nb >> 3);
    const int pb  = gx * gy;
    const int bz  = g / pb;
    const int r   = g - bz * pb;
    const int stpr = gx >> 2;
    const int st  = r >> 4;
    const int w   = r & 15;
    const int sty = st / stpr;
    const int stx = st - sty * stpr;
    const int bx  = (stx << 2) + (w & 3);
    const int by  = (sty << 2) + (w >> 2);

    A += (long)bz * sA;
    B += (long)bz * sB;
    C += (long)bz * sC;

    __shared__ uint16_t As[2][BM * 64];    // 256: 2x32 KB | 128: 2x16 KB
    __shared__ uint16_t Bs[2][256 * 64];   // 2x32 KB

    const int tid = threadIdx.x;
    const int m0 = by * BM;
    const int n0 = bx * 256;

    // ---- staging addresses: thread t covers (row = t>>3, 16B chunk = t&7)
    // of each 64-row region. Source column pre-swizzled: chunk ^ (row&7).
    const int srow = tid >> 3;
    const int sx   = ((tid & 7) ^ (srow & 7)) << 3;   // element offset
    const uint16_t* Ag = A + (long)(m0 + srow) * lda + sx;
    const uint16_t* Bg = B + (long)(n0 + srow) * ldb + sx;

    // ---- fragment-read addresses (swizzled ds_read) ----
    const int wave = tid >> 6, lane = tid & 63;
    const int quad = lane >> 4, l16 = lane & 15;
    const int wm = wave >> 2, wn = wave & 3;          // 2M x 4N wave grid
    const int cs0 = ((quad       ^ (l16 & 7)) << 3);  // k-step 0 chunk
    const int cs1 = (((quad + 4) ^ (l16 & 7)) << 3);  // k-step 1 chunk
    const int axbase = (wm * (BM / 2) + l16) * 64;
    const int bxbase = (wn * 64 + l16) * 64;

    const int nk = K / 64;

    f32x4 acc[MF][4] = {};
    bf16x8 af[MH][2];       // current M-half, 2 k-steps
    bf16x8 bf[2][2][2];     // both N-halves held across all 4 phases

    // ---- prologue: stage tile 0 into buf 0, drain, barrier ----
    stageT<NAC>(Ag, lda, &As[0][0], tid);
    stageT<4>(Bg, ldb, &Bs[0][0], tid);
    asm volatile("s_waitcnt vmcnt(0)" ::: "memory");
    asm volatile("s_barrier" ::: "memory");

    for (int kt = 0; kt < nk; ++kt) {
        const int cur = kt & 1, nxt = cur ^ 1;
        const uint16_t* Asb = &As[cur][0];
        const uint16_t* Bsb = &Bs[cur][0];
        const bool pf = (kt + 1 < nk);
        const long ko = (long)(kt + 1) * 64;

        // phase 0: (mh0, nh0) ; issue next A tile
        DS_A(0); DS_B(0);
        if (pf) stageT<NAC>(Ag + ko, lda, &As[nxt][0], tid);
        PH_ENTER; MMA(0, 0); PH_EXIT;

        // phase 1: (mh0, nh1) ; issue next B tile
        DS_B(1);
        if (pf) stageT<4>(Bg + ko, ldb, &Bs[nxt][0], tid);
        PH_ENTER; MMA(0, 1); PH_EXIT;

        // phase 2: (mh1, nh0)
        DS_A(1);
        PH_ENTER; MMA(1, 0); PH_EXIT;

        // phase 3: (mh1, nh1) ; drain staged loads before buffer swap
        PH_ENTER; MMA(1, 1);
        __builtin_amdgcn_s_setprio(0);
        asm volatile("s_waitcnt vmcnt(0)\n\ts_barrier" ::: "memory");
    }

    // ---- epilogue: C/D layout col = lane&15, row = quad*4 + reg ----
    if (VtP && n0 >= vcol0) {
        // V region: write transposed, Vt[b][e][s]; 4 consecutive rows per
        // lane are contiguous in s -> one packed ushort4 store per (f,j).
        #pragma unroll
        for (int f = 0; f < MF; ++f) {
            const int row0 = m0 + wm * (BM / 2) + f * 16 + quad * 4;
            const int b_   = row0 >> 11;
            const int s_   = row0 & 2047;
            #pragma unroll
            for (int j = 0; j < 4; ++j) {
                const int e = n0 + wn * 64 + j * 16 + l16 - vcol0;
                ushort4 o;
                o.x = f2bf(acc[f][j][0]);
                o.y = f2bf(acc[f][j][1]);
                o.z = f2bf(acc[f][j][2]);
                o.w = f2bf(acc[f][j][3]);
                *(ushort4*)(VtP + ((long)b_ * 1024 + e) * 2048 + s_) = o;
            }
        }
    } else {
        #pragma unroll
        for (int f = 0; f < MF; ++f) {
            #pragma unroll
            for (int j = 0; j < 4; ++j) {
                #pragma unroll
                for (int r4 = 0; r4 < 4; ++r4) {
                    const int row = m0 + wm * (BM / 2) + f * 16 + quad * 4 + r4;
                    const int col = n0 + wn * 64 + j * 16 + l16;
                    const float val = acc[f][j][r4] * alpha;
                    if constexpr (sizeof(OutT) == 2)
                        C[(long)row * ldc + col] = f2bf(val);
                    else
                        C[(long)row * ldc + col] = val;
                }
            }
        }
    }
}

// ---------------------------------------------------------------------------
extern "C" void kernel_launch(void* const* d_in, const int* in_sizes, int n_in,
                              void* d_out, int out_size, void* d_ws, size_t ws_size,
                              hipStream_t stream) {
    const float* x  = (const float*)d_in[0];
    const float* Wq = (const float*)d_in[1];
    const float* Wk = (const float*)d_in[2];
    const float* Wv = (const float*)d_in[3];
    float* out = (float*)d_out;

    const int Bn = 4, S = 2048, E = 1024;
    const long MS = (long)Bn * S;              // 8192 total rows
    const int  N3 = 3 * E;                     // 3072

    // workspace layout (bf16)
    char* ws = (char*)d_ws;
    uint16_t* xb    = (uint16_t*)ws;  ws += (size_t)MS * E * 2;        // 16 MB
    uint16_t* wqkvb = (uint16_t*)ws;  ws += (size_t)N3 * E * 2;        //  6 MB
    uint16_t* QKb   = (uint16_t*)ws;  ws += (size_t)MS * 2048 * 2;     // 32 MB (Q|K, ld=2048)
    uint16_t* Vt    = (uint16_t*)ws;  ws += (size_t)Bn * E * S * 2;    // 16 MB
    uint16_t* Pb    = (uint16_t*)ws;  ws += (size_t)Bn * S * S * 2;    // 32 MB

    // 1) fused cast to bf16 (x + stacked [Wq;Wk;Wv])
    {
        int NX4 = (int)(MS * E / 4);            // 2097152
        int NW4 = E * E / 4;                    // 262144
        int tot = NX4 + 3 * NW4;
        cast_all<<<dim3((tot + 255) / 256), dim3(256), 0, stream>>>(
            x, Wq, Wk, Wv, xb, wqkvb, NX4, NW4);
    }

    // 2) fused QKV: cols [0,2048) -> QKb (ld 2048); cols [2048,3072) -> Vt
    //    transposed (Vt[b][e][s]).  256x256 tiles: 12 x 32 = 384 blocks.
    {
        int gx = N3 / 256, gy = (int)(MS / 256);
        gemm_nt<256, uint16_t><<<dim3(gx * gy), dim3(512), 0, stream>>>(
            xb, wqkvb, QKb, gx, gy, E, E, 2048, E, 1.f, 0, 0, 0,
            Vt, 2048);
    }

    // 3) scores = (Q K^T) / sqrt(E) per batch, bf16 out.
    //    256x256 tiles: 8 x 8 x 4 = 256 blocks (exactly one round).
    {
        int gx = S / 256, gy = S / 256;
        gemm_nt<256, uint16_t><<<dim3(gx * gy * Bn), dim3(512), 0, stream>>>(
            QKb, QKb + 1024, Pb, gx, gy, 2048, 2048, S, E, 0.03125f,
            (long)S * 2048, (long)S * 2048, (long)S * S,
            nullptr, 0);
    }

    // 4) softmax rows in place (4*2048 rows of 2048)
    softmax_rows<<<dim3(Bn * S), dim3(256), 0, stream>>>(Pb);

    // 5) out = P * Vt^T (M=2048, N=1024, K=2048 per batch), fp32 out.
    //    128x256 tiles: 4 x 16 x 4 = 256 blocks (256x256 would only launch
    //    128 blocks and idle half the GPU).
    {
        int gx = E / 256, gy = S / 128;
        gemm_nt<128, float><<<dim3(gx * gy * Bn), dim3(512), 0, stream>>>(
            Pb, Vt, out, gx, gy, S, S, E, S, 1.f,
            (long)S * S, (long)E * S, (long)S * E,
            nullptr, 0);
    }
}

// Round 2
// 252.769 us; speedup vs baseline: 1.0826x; 1.0114x over previous
//
#include <hip/hip_runtime.h>
#include <stdint.h>

// ---------------------------------------------------------------------------
// SelfAttention: out = softmax((x Wq^T)(x Wk^T)^T / sqrt(E)) (x Wv^T)
// B=4, S=2048, E=1024. bf16 MFMA, fp32 accumulate.
// R9: T4 counted-vmcnt pipeline (m218: counted-vs-drain0 = +38..73%).
//  - 64-row gll chunks; tile t+2's chunks issued DURING tile t (same LDS
//    buffer) right after the barrier that retires the last read of each
//    chunk: p1 -> A{0,2}, p2 -> B{0..3}, p3 -> A{1,3}.  Issue stream runs
//    ~1.75 tiles ahead; waits are vmcnt(10) (BM=256) / vmcnt(6) (BM=128),
//    NEVER 0 in the main loop.  Last two tiles peeled with 8/2/0 drains.
//  - QKV switched to BM=128: 12 x 64 = 768 blocks = 3 exact rounds on 256
//    CUs (was 384 = 1.5 rounds, half-idle second round).
// Tiles: QKV 128x256 (768 blk), scores 256x256 (256 blk), PV 128x256 (256).
// Dispatches: cast, QKV, scores, softmax, PV.
// ---------------------------------------------------------------------------

typedef __attribute__((ext_vector_type(8))) short bf16x8;   // 8 bf16 = 4 VGPRs
typedef __attribute__((ext_vector_type(4))) float f32x4;

__device__ __forceinline__ float bf2f(uint16_t u) {
    return __uint_as_float(((uint32_t)u) << 16);
}
__device__ __forceinline__ uint16_t f2bf(float f) {
    uint32_t u = __float_as_uint(f);
    uint32_t r = u + 0x7FFFu + ((u >> 16) & 1u);   // RNE
    return (uint16_t)(r >> 16);
}

// async global -> LDS, 16 bytes per lane (wave-uniform base + lane*16)
__device__ __forceinline__ void gll16(const void* g, void* l) {
    __builtin_amdgcn_global_load_lds(
        (const __attribute__((address_space(1))) uint32_t*)g,
        (__attribute__((address_space(3))) uint32_t*)l,
        16, 0, 0);
}

// ---- fused cast: x (NX4 float4s) then stacked Wq|Wk|Wv (NW4 each) ---------
__global__ __launch_bounds__(256) void cast_all(const float* __restrict__ x,
                                                const float* __restrict__ Wq,
                                                const float* __restrict__ Wk,
                                                const float* __restrict__ Wv,
                                                uint16_t* __restrict__ xb,
                                                uint16_t* __restrict__ wqkvb,
                                                int NX4, int NW4) {
    int i = blockIdx.x * 256 + threadIdx.x;
    const float* src;
    uint16_t* dst;
    int off;
    if (i < NX4) {
        src = x; dst = xb; off = i;
    } else {
        int j = i - NX4;
        if (j >= 3 * NW4) return;
        int which = j / NW4;              // 0,1,2
        off = j - which * NW4;
        src = (which == 0) ? Wq : (which == 1) ? Wk : Wv;
        dst = wqkvb + (size_t)which * NW4 * 4;
    }
    float4 v = ((const float4*)src)[off];
    ushort4 o;
    o.x = f2bf(v.x); o.y = f2bf(v.y); o.z = f2bf(v.z); o.w = f2bf(v.w);
    ((ushort4*)dst)[off] = o;
}

// ---- row softmax over 2048 bf16 elements, in place, one block per row -----
__global__ __launch_bounds__(256) void softmax_rows(uint16_t* __restrict__ P) {
    const int n = 2048;
    uint16_t* row = P + (size_t)blockIdx.x * n;
    int tid = threadIdx.x;
    int w = tid >> 6, ln = tid & 63;
    float v[8];
    float m = -3.4e38f;
    #pragma unroll
    for (int i = 0; i < 8; i++) { v[i] = bf2f(row[tid + 256 * i]); m = fmaxf(m, v[i]); }
    #pragma unroll
    for (int o = 32; o >= 1; o >>= 1) m = fmaxf(m, __shfl_down(m, o, 64));
    __shared__ float smax[4], ssum[4];
    if (ln == 0) smax[w] = m;
    __syncthreads();
    m = fmaxf(fmaxf(smax[0], smax[1]), fmaxf(smax[2], smax[3]));
    float s = 0.f;
    #pragma unroll
    for (int i = 0; i < 8; i++) { v[i] = __expf(v[i] - m); s += v[i]; }
    #pragma unroll
    for (int o = 32; o >= 1; o >>= 1) s += __shfl_down(s, o, 64);
    if (ln == 0) ssum[w] = s;
    __syncthreads();
    s = ssum[0] + ssum[1] + ssum[2] + ssum[3];
    float inv = 1.f / s;
    #pragma unroll
    for (int i = 0; i < 8; i++) row[tid + 256 * i] = f2bf(v[i] * inv);
}

// ---- NT GEMM: C[M][N] = alpha * A[M][K] * B[N][K]^T  (bf16 in, OutT out) --

#define DS_A(mh_) do { \
    _Pragma("unroll") for (int f_ = 0; f_ < MH; ++f_) { \
        const uint16_t* p_ = Asb + axbase + ((mh_)*MH + f_) * 1024; \
        af[f_][0] = *(const bf16x8*)(p_ + cs0); \
        af[f_][1] = *(const bf16x8*)(p_ + cs1); \
    } } while (0)

#define DS_B(nh_) do { \
    _Pragma("unroll") for (int n_ = 0; n_ < 2; ++n_) { \
        const uint16_t* p_ = Bsb + bxbase + ((nh_)*2 + n_) * 1024; \
        bfr[nh_][n_][0] = *(const bf16x8*)(p_ + cs0); \
        bfr[nh_][n_][1] = *(const bf16x8*)(p_ + cs1); \
    } } while (0)

#define MMA(mh_, nh_) do { \
    _Pragma("unroll") for (int f_ = 0; f_ < MH; ++f_) { \
        _Pragma("unroll") for (int n_ = 0; n_ < 2; ++n_) { \
            acc[(mh_)*MH + f_][(nh_)*2 + n_] = __builtin_amdgcn_mfma_f32_16x16x32_bf16( \
                af[f_][0], bfr[nh_][n_][0], acc[(mh_)*MH + f_][(nh_)*2 + n_], 0, 0, 0); \
            acc[(mh_)*MH + f_][(nh_)*2 + n_] = __builtin_amdgcn_mfma_f32_16x16x32_bf16( \
                af[f_][1], bfr[nh_][n_][1], acc[(mh_)*MH + f_][(nh_)*2 + n_], 0, 0, 0); \
        } } } while (0)

#define PH_ENTER do { \
    asm volatile("s_barrier\n\ts_waitcnt lgkmcnt(0)" ::: "memory"); \
    __builtin_amdgcn_s_setprio(1); } while (0)

#define PH_EXIT do { \
    __builtin_amdgcn_s_setprio(0); \
    asm volatile("s_barrier" ::: "memory"); } while (0)

#define VMB(n) asm volatile("s_waitcnt vmcnt(" #n ")\n\ts_barrier" ::: "memory")
#define BARO   asm volatile("s_barrier" ::: "memory")
#define NOBAR  ((void)0)

// One K-tile = 4 phases.  ISSUE: stage tile kt+2's chunks (into buf `cur`,
// legal because each chunk's last read was globally confirmed at the barrier
// preceding its issue point).  W1B/W3B: wait+barrier tokens at p1/p3 exits.
#define KTILE(ISSUE, W1B, W3B) do { \
    const uint16_t* Asb = &As[cur][0]; \
    const uint16_t* Bsb = &Bs[cur][0]; \
    /* p0 */ \
    DS_A(0); DS_B(0); \
    PH_ENTER; MMA(0, 0); PH_EXIT; \
    /* p1: issue next-next A phase0-chunks (free since p0-exit) */ \
    DS_B(1); \
    if constexpr (BM == 256) { if (ISSUE) { stA(cur, ko2, 0); stA(cur, ko2, 2); } } \
    PH_ENTER; MMA(0, 1); __builtin_amdgcn_s_setprio(0); W1B; \
    /* p2: issue next-next B chunks (free since p1-exit) */ \
    DS_A(1); \
    if (ISSUE) { stB(cur, ko2, 0); stB(cur, ko2, 1); stB(cur, ko2, 2); stB(cur, ko2, 3); } \
    PH_ENTER; MMA(1, 0); PH_EXIT; \
    /* p3: issue next-next A phase2-chunks (free since p2-exit) */ \
    if (ISSUE) { \
        if constexpr (BM == 256) { stA(cur, ko2, 1); stA(cur, ko2, 3); } \
        else                     { stA(cur, ko2, 0); stA(cur, ko2, 1); } \
    } \
    PH_ENTER; MMA(1, 1); __builtin_amdgcn_s_setprio(0); W3B; \
} while (0)

template <int BM, typename OutT>
__global__ __launch_bounds__(512, 2) void gemm_nt(const uint16_t* __restrict__ A,
                                                  const uint16_t* __restrict__ B,
                                                  OutT* __restrict__ C,
                                                  int gx, int gy,
                                                  long lda, long ldb, long ldc,
                                                  int K, float alpha,
                                                  long sA, long sB, long sC,
                                                  uint16_t* __restrict__ VtP,
                                                  int vcol0) {
    constexpr int MF = BM / 32;   // M fragments per wave
    constexpr int MH = MF / 2;    // per M-half

    // ---- XCD-contiguous swizzle + 4x4 supertile decode (grids %8==0,
    //      gx%4==0, gy%4==0) ----
    const int total = gridDim.x;
    const int nb  = blockIdx.x;
    const int per = total >> 3;
    const int g   = (nb & 7) * per + (nb >> 3);
    const int pb  = gx * gy;
    const int bz  = g / pb;
    const int r   = g - bz * pb;
    const int stpr = gx >> 2;
    const int st  = r >> 4;
    const int w   = r & 15;
    const int sty = st / stpr;
    const int stx = st - sty * stpr;
    const int bx  = (stx << 2) + (w & 3);
    const int by  = (sty << 2) + (w >> 2);

    A += (long)bz * sA;
    B += (long)bz * sB;
    C += (long)bz * sC;

    __shared__ uint16_t As[2][BM * 64];    // 256: 2x32 KB | 128: 2x16 KB
    __shared__ uint16_t Bs[2][256 * 64];   // 2x32 KB

    const int tid = threadIdx.x;
    const int m0 = by * BM;
    const int n0 = bx * 256;

    // ---- staging addresses: thread t covers (row = t>>3, 16B chunk = t&7)
    // of each 64-row region. Source column pre-swizzled: chunk ^ (row&7).
    const int srow = tid >> 3;
    const int sx   = ((tid & 7) ^ (srow & 7)) << 3;   // element offset
    const uint16_t* Ag = A + (long)(m0 + srow) * lda + sx;
    const uint16_t* Bg = B + (long)(n0 + srow) * ldb + sx;

    // stage one 64-row chunk (8 KB, 1 gll per thread) of tile at col-offset ko
    auto stA = [&](int buf, long ko, int c) {
        gll16(Ag + (long)c * 64 * lda + ko, &As[buf][c * 4096] + tid * 8);
    };
    auto stB = [&](int buf, long ko, int c) {
        gll16(Bg + (long)c * 64 * ldb + ko, &Bs[buf][c * 4096] + tid * 8);
    };

    // ---- fragment-read addresses (swizzled ds_read) ----
    const int wave = tid >> 6, lane = tid & 63;
    const int quad = lane >> 4, l16 = lane & 15;
    const int wm = wave >> 2, wn = wave & 3;          // 2M x 4N wave grid
    const int cs0 = ((quad       ^ (l16 & 7)) << 3);  // k-step 0 chunk
    const int cs1 = (((quad + 4) ^ (l16 & 7)) << 3);  // k-step 1 chunk
    const int axbase = (wm * (BM / 2) + l16) * 64;
    const int bxbase = (wn * 64 + l16) * 64;

    const int nk = K / 64;

    f32x4 acc[MF][4] = {};
    bf16x8 af[MH][2];       // current M-half, 2 k-steps
    bf16x8 bfr[2][2][2];    // both N-halves held across all 4 phases

    // ---- prologue: issue tiles 0 and 1 in steady-state chunk order,
    // counted wait retires only tile0's phase0-deadline chunks ----
    if constexpr (BM == 256) {
        stA(0, 0, 0);  stA(0, 0, 2);
        stB(0, 0, 0);  stB(0, 0, 1);  stB(0, 0, 2);  stB(0, 0, 3);
        stA(0, 0, 1);  stA(0, 0, 3);
        stA(1, 64, 0); stA(1, 64, 2);
        stB(1, 64, 0); stB(1, 64, 1); stB(1, 64, 2); stB(1, 64, 3);
        stA(1, 64, 1); stA(1, 64, 3);
        VMB(10);       // retire t0.{a0,a2,b0..b3}; t0.{a1,a3}+t1 stay in flight
    } else {
        stB(0, 0, 0);  stB(0, 0, 1);  stB(0, 0, 2);  stB(0, 0, 3);
        stA(0, 0, 0);  stA(0, 0, 1);
        stB(1, 64, 0); stB(1, 64, 1); stB(1, 64, 2); stB(1, 64, 3);
        stA(1, 64, 0); stA(1, 64, 1);
        VMB(6);        // retire t0's 6; t1's 6 stay in flight
    }

    int cur = 0;
    for (int kt = 0; kt < nk - 2; ++kt) {
        const long ko2 = (long)(kt + 2) * 64;
        if constexpr (BM == 256) { KTILE(1, VMB(10), VMB(10)); }
        else                     { KTILE(1, BARO,    VMB(6));  }
        cur ^= 1;
    }
    {   // peeled tile nk-2: no issues, partial drain
        const long ko2 = 0; (void)ko2;
        if constexpr (BM == 256) { KTILE(0, VMB(8), VMB(2)); }
        else                     { KTILE(0, BARO,   VMB(0)); }
        cur ^= 1;
    }
    {   // peeled tile nk-1: final tile
        const long ko2 = 0; (void)ko2;
        if constexpr (BM == 256) { KTILE(0, VMB(0), NOBAR); }
        else                     { KTILE(0, BARO,   NOBAR); }
    }

    // ---- epilogue: C/D layout col = lane&15, row = quad*4 + reg ----
    if (VtP && n0 >= vcol0) {
        // V region: write transposed, Vt[b][e][s]; 4 consecutive rows per
        // lane are contiguous in s -> one packed ushort4 store per (f,j).
        #pragma unroll
        for (int f = 0; f < MF; ++f) {
            const int row0 = m0 + wm * (BM / 2) + f * 16 + quad * 4;
            const int b_   = row0 >> 11;
            const int s_   = row0 & 2047;
            #pragma unroll
            for (int j = 0; j < 4; ++j) {
                const int e = n0 + wn * 64 + j * 16 + l16 - vcol0;
                ushort4 o;
                o.x = f2bf(acc[f][j][0]);
                o.y = f2bf(acc[f][j][1]);
                o.z = f2bf(acc[f][j][2]);
                o.w = f2bf(acc[f][j][3]);
                *(ushort4*)(VtP + ((long)b_ * 1024 + e) * 2048 + s_) = o;
            }
        }
    } else {
        #pragma unroll
        for (int f = 0; f < MF; ++f) {
            #pragma unroll
            for (int j = 0; j < 4; ++j) {
                #pragma unroll
                for (int r4 = 0; r4 < 4; ++r4) {
                    const int row = m0 + wm * (BM / 2) + f * 16 + quad * 4 + r4;
                    const int col = n0 + wn * 64 + j * 16 + l16;
                    const float val = acc[f][j][r4] * alpha;
                    if constexpr (sizeof(OutT) == 2)
                        C[(long)row * ldc + col] = f2bf(val);
                    else
                        C[(long)row * ldc + col] = val;
                }
            }
        }
    }
}

// ---------------------------------------------------------------------------
extern "C" void kernel_launch(void* const* d_in, const int* in_sizes, int n_in,
                              void* d_out, int out_size, void* d_ws, size_t ws_size,
                              hipStream_t stream) {
    const float* x  = (const float*)d_in[0];
    const float* Wq = (const float*)d_in[1];
    const float* Wk = (const float*)d_in[2];
    const float* Wv = (const float*)d_in[3];
    float* out = (float*)d_out;

    const int Bn = 4, S = 2048, E = 1024;
    const long MS = (long)Bn * S;              // 8192 total rows
    const int  N3 = 3 * E;                     // 3072

    // workspace layout (bf16)
    char* ws = (char*)d_ws;
    uint16_t* xb    = (uint16_t*)ws;  ws += (size_t)MS * E * 2;        // 16 MB
    uint16_t* wqkvb = (uint16_t*)ws;  ws += (size_t)N3 * E * 2;        //  6 MB
    uint16_t* QKb   = (uint16_t*)ws;  ws += (size_t)MS * 2048 * 2;     // 32 MB (Q|K, ld=2048)
    uint16_t* Vt    = (uint16_t*)ws;  ws += (size_t)Bn * E * S * 2;    // 16 MB
    uint16_t* Pb    = (uint16_t*)ws;  ws += (size_t)Bn * S * S * 2;    // 32 MB

    // 1) fused cast to bf16 (x + stacked [Wq;Wk;Wv])
    {
        int NX4 = (int)(MS * E / 4);            // 2097152
        int NW4 = E * E / 4;                    // 262144
        int tot = NX4 + 3 * NW4;
        cast_all<<<dim3((tot + 255) / 256), dim3(256), 0, stream>>>(
            x, Wq, Wk, Wv, xb, wqkvb, NX4, NW4);
    }

    // 2) fused QKV: cols [0,2048) -> QKb (ld 2048); cols [2048,3072) -> Vt
    //    transposed (Vt[b][e][s]).  128x256 tiles: 12 x 64 = 768 blocks
    //    = 3 exact rounds on 256 CUs.
    {
        int gx = N3 / 256, gy = (int)(MS / 128);
        gemm_nt<128, uint16_t><<<dim3(gx * gy), dim3(512), 0, stream>>>(
            xb, wqkvb, QKb, gx, gy, E, E, 2048, E, 1.f, 0, 0, 0,
            Vt, 2048);
    }

    // 3) scores = (Q K^T) / sqrt(E) per batch, bf16 out.
    //    256x256 tiles: 8 x 8 x 4 = 256 blocks (exactly one round).
    {
        int gx = S / 256, gy = S / 256;
        gemm_nt<256, uint16_t><<<dim3(gx * gy * Bn), dim3(512), 0, stream>>>(
            QKb, QKb + 1024, Pb, gx, gy, 2048, 2048, S, E, 0.03125f,
            (long)S * 2048, (long)S * 2048, (long)S * S,
            nullptr, 0);
    }

    // 4) softmax rows in place (4*2048 rows of 2048)
    softmax_rows<<<dim3(Bn * S), dim3(256), 0, stream>>>(Pb);

    // 5) out = P * Vt^T (M=2048, N=1024, K=2048 per batch), fp32 out.
    //    128x256 tiles: 4 x 16 x 4 = 256 blocks (one round).
    {
        int gx = E / 256, gy = S / 128;
        gemm_nt<128, float><<<dim3(gx * gy * Bn), dim3(512), 0, stream>>>(
            Pb, Vt, out, gx, gy, S, S, E, S, 1.f,
            (long)S * S, (long)E * S, (long)S * E,
            nullptr, 0);
    }
}